// Round 1
// 277.408 us; speedup vs baseline: 1.2609x; 1.2609x over previous
//
#include <hip/hip_runtime.h>
#include <stdint.h>

// Problem constants
#define NJ 192                    // N1
#define OUT_HALF 12582912         // B*HN*N1 = 4096*16*192

// LDS strides (elements)
#define XS 520                    // X tile (bf16): 32 x 520 rows (512 data + pad)
#define HS 264                    // H tile (bf16): 32 x 264
#define OS 516                    // O tile (f32):  32 x 516 (overlay)

// Arena layout (bytes). 66560 total -> 2 blocks/CU (2x66560 = 133120 <= 160K).
//   sX  [0, 33280)          bf16 32x520
//   sW1 [33280, 49664)      one K=32 frag-contiguous W1 chunk (16384 B)
//   sH  [49664, 66560)      bf16 32x264
//   sW2 [0, 32768)          one K=32 frag-contiguous W2 chunk, overlays dead X
//   sO  [0, 66048)          f32 32x516, overlays everything after GEMM2
#define W1_OFF 33280
#define H_OFF  49664
#define ARENA  66560

typedef __attribute__((ext_vector_type(4))) float    f32x4;
typedef __attribute__((ext_vector_type(4))) int      i32x4;
typedef __attribute__((ext_vector_type(4))) uint32_t u32x4;
typedef __attribute__((ext_vector_type(8))) short    bf16x8;

__device__ __forceinline__ float bf2f(short u) {
    union { float f; uint32_t i; } c;
    c.i = ((uint32_t)(uint16_t)u) << 16;
    return c.f;
}
// HW packed f32->bf16 (RNE), 1 instr for 2 converts (vs 5-op software RNE)
__device__ __forceinline__ uint32_t cvt_pk_bf16(float lo, float hi) {
    uint32_t r;
    asm("v_cvt_pk_bf16_f32 %0, %1, %2" : "=v"(r) : "v"(lo), "v"(hi));
    return r;
}
// async global->LDS, 16B per lane; LDS dest must be the wave-uniform base
// (HW adds lane*16). __syncthreads() drains vmcnt, so no explicit waitcnt.
__device__ __forceinline__ void gload16(const void* g, void* l) {
    __builtin_amdgcn_global_load_lds(
        (const __attribute__((address_space(1))) uint32_t*)g,
        (__attribute__((address_space(3))) uint32_t*)l, 16, 0, 0);
}

// ---------------------------------------------------------------------------
// Pre-kernel: convert W1/W2 f32 -> bf16, packed FRAG-CONTIGUOUS per K=32 chunk
// so main-kernel staging is linear global_load_lds (no padding, no VALU).
//   P1 (ws+0):      16 chunks; chunk c, unit u(0..1023): nt=u>>6, lane=u&63
//       elems = W1[nt*16 + (lane&15)][c*32 + (lane>>4)*8 + 0..7]
//   P2 (ws+131072):  8 chunks; chunk c, unit u(0..2047): nt=u>>6, lane=u&63
//       elems = W2[nt*16 + (lane&15)][c*32 + (lane>>4)*8 + 0..7]
// 32768 threads, one 8-elem unit each.
// ---------------------------------------------------------------------------
__global__ __launch_bounds__(256)
void pack_weights(const float* __restrict__ W1, const float* __restrict__ W2,
                  short* __restrict__ ws) {
    int id = blockIdx.x * 256 + threadIdx.x;     // 0..32767
    const float* src;
    short* dst;
    if (id < 16384) {              // P1: 16 chunks x 1024 units
        int c = id >> 10, u = id & 1023;
        int nt = u >> 6, lane = u & 63;
        src = W1 + (nt * 16 + (lane & 15)) * 512 + c * 32 + (lane >> 4) * 8;
        dst = ws + id * 8;
    } else {                       // P2: 8 chunks x 2048 units
        int id2 = id - 16384;
        int c = id2 >> 11, u = id2 & 2047;
        int nt = u >> 6, lane = u & 63;
        src = W2 + (nt * 16 + (lane & 15)) * 256 + c * 32 + (lane >> 4) * 8;
        dst = ws + 131072 + id2 * 8;
    }
    f32x4 a = *(const f32x4*)src;
    f32x4 b = *(const f32x4*)(src + 4);
    u32x4 o;
    o[0] = cvt_pk_bf16(a[0], a[1]);
    o[1] = cvt_pk_bf16(a[2], a[3]);
    o[2] = cvt_pk_bf16(b[0], b[1]);
    o[3] = cvt_pk_bf16(b[2], b[3]);
    *(u32x4*)dst = o;
}

// ---------------------------------------------------------------------------
// Main kernel. One block: 32 rows (2 batches x 16 heads), 512 threads =
// 8 waves = (2 m-tiles) x (4 N-quarters). 66560 B LDS -> 2 blocks/CU so two
// independent blocks overlap phases (staging latency / barrier drains hide
// under the other block's compute). Fused scatter -> LN -> GEMM1(relu) ->
// GEMM2(sigmoid) -> gather.
// ---------------------------------------------------------------------------
__global__ __launch_bounds__(512, 4)
void fused_mlp(const float* __restrict__ rgb,
               const float* __restrict__ tir,
               const int*  __restrict__ gidx,
               const float* __restrict__ ln_g,
               const float* __restrict__ ln_b,
               const short* __restrict__ P1,   // packed bf16 W1 chunks
               const float* __restrict__ b1,   // (256)
               const short* __restrict__ P2,   // packed bf16 W2 chunks
               const float* __restrict__ b2,   // (512)
               float* __restrict__ out)        // rgb half then tir half, f32
{
    __shared__ __attribute__((aligned(16))) char arena[ARENA];
    short* sX  = (short*)arena;
    short* sW1 = (short*)(arena + W1_OFF);
    short* sH  = (short*)(arena + H_OFF);
    short* sW2 = (short*)arena;          // overlays dead X during GEMM2
    float* sO  = (float*)arena;          // overlays everything after GEMM2

    const int tid  = threadIdx.x;
    const int blk  = blockIdx.x;
    const int row0 = blk * 32;           // global row = b*16 + h
    const int b0   = blk * 2;
    const int wave = tid >> 6;
    const int lane = tid & 63;
    const int lr   = lane & 15;          // fragment row (A) / col (B,D)
    const int quad = lane >> 4;          // 0..3
    const int mw   = wave & 1;           // m-tile (16 rows)
    const int nw   = wave >> 1;          // N-quarter

    const char* P1b = (const char*)P1;
    const char* P2b = (const char*)P2;
    char* w1dst = arena + W1_OFF + wave * 1024;   // + k*8192, wave-uniform
    char* w2dst = arena + wave * 1024;            // + k*8192, wave-uniform

    // Prefetch W1 chunk 0 immediately: its L2 latency hides under zero+scatter+LN.
    // (sW1 region is untouched until GEMM1.)
    #pragma unroll
    for (int k = 0; k < 2; ++k)
        gload16(P1b + (k * 512 + tid) * 16, w1dst + k * 8192);

    // ---- Phase 0: zero X, then scatter f32->bf16 through gidx ----
    {
        u32x4* xz = (u32x4*)sX;
        for (int u = tid; u < 2080; u += 512) xz[u] = (u32x4){0u, 0u, 0u, 0u};
    }
    __syncthreads();

    i32x4 ivs[3];   // keep gidx values in registers for the final gather
    #pragma unroll
    for (int it = 0; it < 3; ++it) {
        int p = (it * 512 + tid) * 4;    // 0..6140, 4-elem groups never cross rows
        int r = p / NJ;
        int j = p - r * NJ;
        ivs[it] = *(const i32x4*)&gidx[(b0 + (r >> 4)) * NJ + j];
        f32x4 vr = *(const f32x4*)&rgb[(row0 + r) * NJ + j];
        f32x4 vt = *(const f32x4*)&tir[(row0 + r) * NJ + j];
        short* xr = sX + r * XS;
        #pragma unroll
        for (int e = 0; e < 4; ++e) {
            uint32_t pk = cvt_pk_bf16(vr[e], vt[e]);   // lo=rgb, hi=tir
            xr[ivs[it][e]]       = (short)pk;
            xr[256 + ivs[it][e]] = (short)(pk >> 16);
        }
    }
    __syncthreads();

    // ---- Phase 0.5: LayerNorm over 512 per row; 16 threads per row ----
    {
        int r = tid >> 4, sub = tid & 15;
        short* xr = sX + r * XS + sub * 32;
        float s = 0.f, ss = 0.f;
        #pragma unroll
        for (int t = 0; t < 4; ++t) {
            bf16x8 v8 = *(bf16x8*)(xr + t * 8);
            #pragma unroll
            for (int e = 0; e < 8; ++e) { float v = bf2f(v8[e]); s += v; ss += v * v; }
        }
        s += __shfl_xor(s, 1, 16);  ss += __shfl_xor(ss, 1, 16);
        s += __shfl_xor(s, 2, 16);  ss += __shfl_xor(ss, 2, 16);
        s += __shfl_xor(s, 4, 16);  ss += __shfl_xor(ss, 4, 16);
        s += __shfl_xor(s, 8, 16);  ss += __shfl_xor(ss, 8, 16);
        float mu  = s * (1.f / 512.f);
        float var = ss * (1.f / 512.f) - mu * mu;
        float rs  = rsqrtf(var + 1e-5f);
        const float* gp = ln_g + sub * 32;
        const float* bp = ln_b + sub * 32;
        #pragma unroll
        for (int t = 0; t < 4; ++t) {
            bf16x8 v8 = *(bf16x8*)(xr + t * 8);
            f32x4 g0 = *(const f32x4*)(gp + t * 8);
            f32x4 g1 = *(const f32x4*)(gp + t * 8 + 4);
            f32x4 c0 = *(const f32x4*)(bp + t * 8);
            f32x4 c1 = *(const f32x4*)(bp + t * 8 + 4);
            float y0 = (bf2f(v8[0]) - mu) * rs * g0[0] + c0[0];
            float y1 = (bf2f(v8[1]) - mu) * rs * g0[1] + c0[1];
            float y2 = (bf2f(v8[2]) - mu) * rs * g0[2] + c0[2];
            float y3 = (bf2f(v8[3]) - mu) * rs * g0[3] + c0[3];
            float y4 = (bf2f(v8[4]) - mu) * rs * g1[0] + c1[0];
            float y5 = (bf2f(v8[5]) - mu) * rs * g1[1] + c1[1];
            float y6 = (bf2f(v8[6]) - mu) * rs * g1[2] + c1[2];
            float y7 = (bf2f(v8[7]) - mu) * rs * g1[3] + c1[3];
            u32x4 w;
            w[0] = cvt_pk_bf16(y0, y1);
            w[1] = cvt_pk_bf16(y2, y3);
            w[2] = cvt_pk_bf16(y4, y5);
            w[3] = cvt_pk_bf16(y6, y7);
            *(u32x4*)(xr + t * 8) = w;
        }
    }

    // ---- Phase 1: H(32x256) = relu(X @ W1^T + b1), K=512 in 16 chunks of 32 ----
    f32x4 acc1[4];
    #pragma unroll
    for (int i = 0; i < 4; ++i) acc1[i] = (f32x4){0.f, 0.f, 0.f, 0.f};

    const short* xrow   = sX + (mw * 16 + lr) * XS + quad * 8;
    const short* wfrag1 = sW1 + (nw * 4 * 64 + lane) * 8;   // frag-contiguous

    for (int c = 0; c < 16; ++c) {
        __syncthreads();              // stage(c) drained (syncthreads waits vmcnt) + LN/prev reads done
        bf16x8 a = *(const bf16x8*)(xrow + c * 32);
        #pragma unroll
        for (int i = 0; i < 4; ++i) {
            bf16x8 b = *(const bf16x8*)(wfrag1 + i * 512);
            acc1[i] = __builtin_amdgcn_mfma_f32_16x16x32_bf16(a, b, acc1[i], 0, 0, 0);
        }
        __syncthreads();              // all waves done reading sW1
        if (c < 15) {
            #pragma unroll
            for (int k = 0; k < 2; ++k)
                gload16(P1b + (c + 1) * 16384 + (k * 512 + tid) * 16, w1dst + k * 8192);
        }
    }

    // Prefetch W2 chunk 0 into dead X region; latency hides under epilogue 1.
    #pragma unroll
    for (int k = 0; k < 4; ++k)
        gload16(P2b + (k * 512 + tid) * 16, w2dst + k * 8192);

    // epilogue 1: bias + relu -> bf16 H (C/D layout: col=lr, row=quad*4+rr)
    #pragma unroll
    for (int i = 0; i < 4; ++i) {
        int col = (nw * 4 + i) * 16 + lr;
        float bias = b1[col];
        #pragma unroll
        for (int rr = 0; rr < 4; ++rr) {
            int row = mw * 16 + quad * 4 + rr;
            float h = fmaxf(acc1[i][rr] + bias, 0.f);
            sH[row * HS + col] = (short)cvt_pk_bf16(h, h);
        }
    }

    // ---- Phase 2: O(32x512) = sigmoid(H @ W2^T + b2), K=256 in 8 chunks of 32 ----
    f32x4 acc2[8];
    #pragma unroll
    for (int i = 0; i < 8; ++i) acc2[i] = (f32x4){0.f, 0.f, 0.f, 0.f};

    const short* hrow   = sH + (mw * 16 + lr) * HS + quad * 8;
    const short* wfrag2 = sW2 + (nw * 8 * 64 + lane) * 8;

    for (int c = 0; c < 8; ++c) {
        __syncthreads();              // H writes + stage2(c) visible
        bf16x8 a = *(const bf16x8*)(hrow + c * 32);
        #pragma unroll
        for (int i = 0; i < 8; ++i) {
            bf16x8 b = *(const bf16x8*)(wfrag2 + i * 512);
            acc2[i] = __builtin_amdgcn_mfma_f32_16x16x32_bf16(a, b, acc2[i], 0, 0, 0);
        }
        __syncthreads();              // all waves done reading sW2
        if (c < 7) {
            #pragma unroll
            for (int k = 0; k < 4; ++k)
                gload16(P2b + (c + 1) * 32768 + (k * 512 + tid) * 16, w2dst + k * 8192);
        }
    }

    // epilogue 2: bias + sigmoid -> f32 O (overlays arena; X/W/H all dead)
    #pragma unroll
    for (int i = 0; i < 8; ++i) {
        int col = (nw * 8 + i) * 16 + lr;
        float bias = b2[col];
        #pragma unroll
        for (int rr = 0; rr < 4; ++rr) {
            int row = mw * 16 + quad * 4 + rr;
            float x = acc2[i][rr] + bias;
            sO[row * OS + col] = 1.f / (1.f + __expf(-x));
        }
    }
    __syncthreads();

    // ---- Phase 3: gather through registered gidx, vectorized f32x4 stores ----
    #pragma unroll
    for (int it = 0; it < 3; ++it) {
        int p = (it * 512 + tid) * 4;
        int r = p / NJ;
        int j = p - r * NJ;
        const float* orow = sO + r * OS;
        f32x4 vr, vt;
        #pragma unroll
        for (int e = 0; e < 4; ++e) {
            vr[e] = orow[ivs[it][e]];
            vt[e] = orow[256 + ivs[it][e]];
        }
        *(f32x4*)&out[(row0 + r) * NJ + j]            = vr;
        *(f32x4*)&out[OUT_HALF + (row0 + r) * NJ + j] = vt;
    }
}

extern "C" void kernel_launch(void* const* d_in, const int* in_sizes, int n_in,
                              void* d_out, int out_size, void* d_ws, size_t ws_size,
                              hipStream_t stream) {
    const float* rgb  = (const float*)d_in[0];
    const float* tir  = (const float*)d_in[1];
    const int*   gidx = (const int*)d_in[2];
    const float* ln_g = (const float*)d_in[3];
    const float* ln_b = (const float*)d_in[4];
    const float* W1   = (const float*)d_in[5];
    const float* b1   = (const float*)d_in[6];
    const float* W2   = (const float*)d_in[7];
    const float* b2   = (const float*)d_in[8];
    float* out = (float*)d_out;
    short* wsp = (short*)d_ws;     // needs 512 KB: P1 at 0, P2 at elem 131072

    pack_weights<<<128, 256, 0, stream>>>(W1, W2, wsp);
    fused_mlp<<<2048, 512, 0, stream>>>(rgb, tir, gidx, ln_g, ln_b,
                                        wsp, b1, wsp + 131072, b2, out);
}

// Round 2
// 270.039 us; speedup vs baseline: 1.2953x; 1.0273x over previous
//
#include <hip/hip_runtime.h>
#include <stdint.h>

// Problem constants
#define NJ 192                    // N1
#define OUT_HALF 12582912         // B*HN*N1 = 4096*16*192

// LDS geometry (elements)
#define XS 520      // X: 64 x 520 bf16 (interleaved rgb/tir pairs: il col 2k=rgb_k, 2k+1=tir_k)
#define HS 264      // H: 64 x 264 bf16 (row stride 528B = 33*16, bank shift 4)
#define OSD 516     // O: 32 x 516 f32 per row-half pass (stride 2064B, bank shift 4)

// Arena byte layout (67584 total -> 2 blocks/CU):
//   sX    [0, 66560)        64x520 bf16, dies after A1 frag load
//   slots [0, 32768)        two 16KB weight slots (overlay dead sX)
//   sH    [33280, 67072)    64x264 bf16
//   sStat [67072, 67584)    64 x {rs, mu*rs} f32  (outside sX! live from scatter to epi1)
//   sO    [0, 66048)        32x516 f32 overlay, after GEMM2
#define SLOTB  16384
#define H_OFF  33280
#define STAT_OFF 67072
#define ARENA  67584

typedef __attribute__((ext_vector_type(4))) float    f32x4;
typedef __attribute__((ext_vector_type(2))) float    f32x2;
typedef __attribute__((ext_vector_type(4))) int      i32x4;
typedef __attribute__((ext_vector_type(4))) uint32_t u32x4;
typedef __attribute__((ext_vector_type(8))) short    bf16x8;

// u1[d] = b1[d] + sum_e W1[d][e]*ln_b[e];  v1[d] = sum_e W1[d][e]*ln_g[e]
__device__ float g_u1[256];
__device__ float g_v1[256];

// HW packed f32->bf16 (RNE)
__device__ __forceinline__ uint32_t cvt_pk_bf16(float lo, float hi) {
    uint32_t r;
    asm("v_cvt_pk_bf16_f32 %0, %1, %2" : "=v"(r) : "v"(lo), "v"(hi));
    return r;
}
// async global->LDS, 16B/lane; LDS dest is wave-uniform base (HW adds lane*16)
__device__ __forceinline__ void gload16(const void* g, void* l) {
    __builtin_amdgcn_global_load_lds(
        (const __attribute__((address_space(1))) uint32_t*)g,
        (__attribute__((address_space(3))) uint32_t*)l, 16, 0, 0);
}

// ---------------------------------------------------------------------------
// Pre-kernel: pack W1 (g-folded, K-interleaved) and W2 (output-row-interleaved)
// into frag-contiguous parity units; compute u1/v1 into device globals.
//  P1: 32 units (c=K-chunk 0..15, h=tile parity) of 8KB: unit holds 8 n-tiles
//      nt=2*t2+h; elem id = unit*4096 + (t2*64+lane)*8; frag elems are
//      W1'[nt*16+(lane&15)][il K-cols c*32+(lane>>4)*8 ..+7], W1'=W1*g(col).
//  P2: 16 units (c=K-chunk 0..7, h) of 16KB: 16 tiles nt=2*t2+h of the 32
//      interleaved output rows r'=nt*16+(lane&15), orig=(r'>>1)+(r'&1)*256.
// ---------------------------------------------------------------------------
__global__ __launch_bounds__(256)
void pack_weights(const float* __restrict__ W1, const float* __restrict__ W2,
                  const float* __restrict__ ln_g, const float* __restrict__ ln_b,
                  const float* __restrict__ b1, short* __restrict__ ws) {
    if (blockIdx.x == 128) {            // u1 / v1 block
        int d = threadIdx.x;            // 0..255
        float u = b1[d], v = 0.f;
        const float* wr = W1 + d * 512;
        for (int e = 0; e < 512; e += 4) {
            f32x4 w4 = *(const f32x4*)(wr + e);
            f32x4 g4 = *(const f32x4*)(ln_g + e);
            f32x4 l4 = *(const f32x4*)(ln_b + e);
            #pragma unroll
            for (int t = 0; t < 4; ++t) { v += w4[t] * g4[t]; u += w4[t] * l4[t]; }
        }
        g_u1[d] = u; g_v1[d] = v;
        return;
    }
    int id = blockIdx.x * 256 + threadIdx.x;     // 0..32767
    if (id < 16384) {                   // P1
        int u8 = id >> 9, w = id & 511;
        int c = u8 >> 1, h = u8 & 1;
        int t2 = w >> 6, lane = w & 63;
        int nt = 2 * t2 + h;
        int row = nt * 16 + (lane & 15);
        int k0 = c * 16 + ((lane >> 4) << 2);     // orig rgb col base
        f32x4 a  = *(const f32x4*)(W1 + row * 512 + k0);
        f32x4 b  = *(const f32x4*)(W1 + row * 512 + 256 + k0);
        f32x4 ga = *(const f32x4*)(ln_g + k0);
        f32x4 gb = *(const f32x4*)(ln_g + 256 + k0);
        u32x4 o;
        #pragma unroll
        for (int t = 0; t < 4; ++t) o[t] = cvt_pk_bf16(a[t] * ga[t], b[t] * gb[t]);
        *(u32x4*)(ws + id * 8) = o;
    } else {                            // P2
        int id2 = id - 16384;
        int u16 = id2 >> 10, w = id2 & 1023;
        int c = u16 >> 1, h = u16 & 1;
        int t2 = w >> 6, lane = w & 63;
        int nt = 2 * t2 + h;
        int rp = nt * 16 + (lane & 15);           // interleaved output row
        int orow = (rp >> 1) + (rp & 1) * 256;
        int k0 = c * 32 + ((lane >> 4) << 3);
        f32x4 a = *(const f32x4*)(W2 + orow * 256 + k0);
        f32x4 b = *(const f32x4*)(W2 + orow * 256 + k0 + 4);
        u32x4 o;
        o[0] = cvt_pk_bf16(a[0], a[1]);
        o[1] = cvt_pk_bf16(a[2], a[3]);
        o[2] = cvt_pk_bf16(b[0], b[1]);
        o[3] = cvt_pk_bf16(b[2], b[3]);
        *(u32x4*)(ws + 131072 + id2 * 8) = o;
    }
}

// ---------------------------------------------------------------------------
// Main kernel. One block: 64 rows (4 batches x 16 heads), 512 threads =
// 8 waves = 4m x 2n. A-operands register-resident; weights double-buffered
// through two 16KB LDS slots with one barrier per K-unit. LN folded into
// scatter stats + epilogue-1 affine (u1/v1). 67584B LDS -> 2 blocks/CU.
// ---------------------------------------------------------------------------
__global__ __launch_bounds__(512, 4)
void fused_mlp(const float* __restrict__ rgb,
               const float* __restrict__ tir,
               const int*  __restrict__ gidx,
               const short* __restrict__ P1,
               const short* __restrict__ P2,
               const float* __restrict__ b2,
               float* __restrict__ out)
{
    __shared__ __attribute__((aligned(16))) char arena[ARENA];
    short* sX    = (short*)arena;
    short* sH    = (short*)(arena + H_OFF);
    float* sStat = (float*)(arena + STAT_OFF);
    float* sO    = (float*)arena;

    const int tid  = threadIdx.x;
    const int blk  = blockIdx.x;
    const int row0 = blk * 64;          // global row = b*16 + h
    const int b0   = blk * 4;
    const int wave = tid >> 6;
    const int lane = tid & 63;
    const int lr   = lane & 15;
    const int quad = lane >> 4;
    const int mw   = wave & 3;          // m-tile (16 rows)
    const int nw   = wave >> 2;         // n-half

    const char* P1b = (const char*)P1;
    const char* P2b = (const char*)P2;

    // ---- Phase 0: zero X data dwords (pad never read) ----
    {
        uint32_t* xd = (uint32_t*)sX;
        #pragma unroll
        for (int i = 0; i < 8; ++i) {
            int u = i * 512 + tid;               // 4096 groups of 4 dwords
            int r = u >> 6, g = u & 63;
            *(u32x4*)(xd + r * 260 + g * 4) = (u32x4){0u, 0u, 0u, 0u};
        }
    }
    __syncthreads();

    // ---- Phase 1: fused scatter (raw bf16, interleaved) + LN stats ----
    {
        int r = tid >> 3, sub = tid & 7;         // 8 threads per row
        int j0 = sub * 24;
        uint32_t* xdw = (uint32_t*)(sX + r * XS);
        const int*   gp = gidx + (b0 + (r >> 4)) * NJ + j0;
        const float* rp = rgb + (row0 + r) * NJ + j0;
        const float* tp = tir + (row0 + r) * NJ + j0;
        float s = 0.f, ss = 0.f;
        #pragma unroll
        for (int q = 0; q < 6; ++q) {
            i32x4 iv = *(const i32x4*)(gp + q * 4);
            f32x4 vr = *(const f32x4*)(rp + q * 4);
            f32x4 vt = *(const f32x4*)(tp + q * 4);
            #pragma unroll
            for (int e = 0; e < 4; ++e) {
                s  += vr[e] + vt[e];
                ss += vr[e] * vr[e] + vt[e] * vt[e];
                xdw[iv[e]] = cvt_pk_bf16(vr[e], vt[e]);   // lo=rgb, hi=tir
            }
        }
        s  += __shfl_xor(s, 1, 8);  ss += __shfl_xor(ss, 1, 8);
        s  += __shfl_xor(s, 2, 8);  ss += __shfl_xor(ss, 2, 8);
        s  += __shfl_xor(s, 4, 8);  ss += __shfl_xor(ss, 4, 8);
        float mu  = s * (1.f / 512.f);
        float var = ss * (1.f / 512.f) - mu * mu;
        float rs  = rsqrtf(var + 1e-5f);
        if (sub == 0) { sStat[2 * r] = rs; sStat[2 * r + 1] = mu * rs; }
    }
    __syncthreads();

    // ---- A1 fragments -> registers (sX dies after this) ----
    bf16x8 a1[16];
    {
        const short* xr = sX + (mw * 16 + lr) * XS + quad * 8;
        #pragma unroll
        for (int c = 0; c < 16; ++c) a1[c] = *(const bf16x8*)(xr + c * 32);
    }
    __syncthreads();                    // sX dead; slots usable

    // warm the weight pipeline: units 0,1 into slots 0,1
    gload16(P1b + 0 * 8192 + tid * 16, arena + 0       + wave * 1024);
    gload16(P1b + 1 * 8192 + tid * 16, arena + SLOTB   + wave * 1024);
    __syncthreads();                    // drain both stages

    // ---- GEMM1: H(64x256) = X @ W1'^T, K=512 as 32 parity units of 8KB ----
    f32x4 acc1[8];
    #pragma unroll
    for (int i = 0; i < 8; ++i) acc1[i] = (f32x4){0.f, 0.f, 0.f, 0.f};

    const short* wb = (const short*)arena + lane * 8;   // lane*16 bytes

    #pragma unroll
    for (int j = 0; j < 32; ++j) {
        const int c = j >> 1, h = j & 1;
        // read this unit's 4 frags (t2 = nw*4+i2) BEFORE the barrier
        bf16x8 w0 = *(const bf16x8*)(wb + (j & 1) * 8192 + (nw * 4 + 0) * 512);
        bf16x8 w1 = *(const bf16x8*)(wb + (j & 1) * 8192 + (nw * 4 + 1) * 512);
        bf16x8 w2 = *(const bf16x8*)(wb + (j & 1) * 8192 + (nw * 4 + 2) * 512);
        bf16x8 w3 = *(const bf16x8*)(wb + (j & 1) * 8192 + (nw * 4 + 3) * 512);
        __syncthreads();   // drains stage(j+1); all waves done reading slot(j&1)
        if (j <= 29) {
            gload16(P1b + (j + 2) * 8192 + tid * 16,
                    arena + (j & 1) * SLOTB + wave * 1024);
        } else {
            // j=30,31: warm GEMM2's units 0,1 into the just-freed slots
            const int u = j - 30;
            gload16(P2b + u * 16384 + tid * 16,
                    arena + u * SLOTB + wave * 1024);
            gload16(P2b + u * 16384 + 8192 + tid * 16,
                    arena + u * SLOTB + 8192 + wave * 1024);
        }
        acc1[0 + h] = __builtin_amdgcn_mfma_f32_16x16x32_bf16(a1[c], w0, acc1[0 + h], 0, 0, 0);
        acc1[2 + h] = __builtin_amdgcn_mfma_f32_16x16x32_bf16(a1[c], w1, acc1[2 + h], 0, 0, 0);
        acc1[4 + h] = __builtin_amdgcn_mfma_f32_16x16x32_bf16(a1[c], w2, acc1[4 + h], 0, 0, 0);
        acc1[6 + h] = __builtin_amdgcn_mfma_f32_16x16x32_bf16(a1[c], w3, acc1[6 + h], 0, 0, 0);
    }

    // ---- Epilogue 1: h = rs*acc + (u1 - mu*rs*v1), relu -> bf16 sH ----
    {
        const int baserow = mw * 16 + quad * 4;
        float rsv[4], mrs[4];
        #pragma unroll
        for (int rr = 0; rr < 4; ++rr) {
            rsv[rr] = sStat[2 * (baserow + rr)];
            mrs[rr] = sStat[2 * (baserow + rr) + 1];
        }
        #pragma unroll
        for (int i = 0; i < 8; ++i) {
            int col = (nw * 8 + i) * 16 + lr;
            float u1c = g_u1[col], v1c = g_v1[col];
            #pragma unroll
            for (int rr = 0; rr < 4; ++rr) {
                float hh = rsv[rr] * acc1[i][rr] + (u1c - mrs[rr] * v1c);
                hh = fmaxf(hh, 0.f);
                sH[(baserow + rr) * HS + col] = (short)cvt_pk_bf16(hh, hh);
            }
        }
    }
    __syncthreads();                    // sH visible; drains W2 units 0,1

    // ---- GEMM2: O'(64x512) = H @ W2'^T, K=256 as 16 parity units of 16KB ----
    f32x4 acc2[16];
    #pragma unroll
    for (int i = 0; i < 16; ++i) acc2[i] = (f32x4){0.f, 0.f, 0.f, 0.f};

    const short* hrow = sH + (mw * 16 + lr) * HS + quad * 8;

    #pragma unroll
    for (int j = 0; j < 16; ++j) {
        const int c = j >> 1, h = j & 1;
        bf16x8 a = *(const bf16x8*)(hrow + c * 32);
        bf16x8 w0 = *(const bf16x8*)(wb + (j & 1) * 8192 + (nw * 8 + 0) * 512);
        bf16x8 w1 = *(const bf16x8*)(wb + (j & 1) * 8192 + (nw * 8 + 1) * 512);
        bf16x8 w2 = *(const bf16x8*)(wb + (j & 1) * 8192 + (nw * 8 + 2) * 512);
        bf16x8 w3 = *(const bf16x8*)(wb + (j & 1) * 8192 + (nw * 8 + 3) * 512);
        bf16x8 w4 = *(const bf16x8*)(wb + (j & 1) * 8192 + (nw * 8 + 4) * 512);
        bf16x8 w5 = *(const bf16x8*)(wb + (j & 1) * 8192 + (nw * 8 + 5) * 512);
        bf16x8 w6 = *(const bf16x8*)(wb + (j & 1) * 8192 + (nw * 8 + 6) * 512);
        bf16x8 w7 = *(const bf16x8*)(wb + (j & 1) * 8192 + (nw * 8 + 7) * 512);
        __syncthreads();
        if (j <= 13) {
            gload16(P2b + (j + 2) * 16384 + tid * 16,
                    arena + (j & 1) * SLOTB + wave * 1024);
            gload16(P2b + (j + 2) * 16384 + 8192 + tid * 16,
                    arena + (j & 1) * SLOTB + 8192 + wave * 1024);
        }
        acc2[0  + h] = __builtin_amdgcn_mfma_f32_16x16x32_bf16(a, w0, acc2[0  + h], 0, 0, 0);
        acc2[2  + h] = __builtin_amdgcn_mfma_f32_16x16x32_bf16(a, w1, acc2[2  + h], 0, 0, 0);
        acc2[4  + h] = __builtin_amdgcn_mfma_f32_16x16x32_bf16(a, w2, acc2[4  + h], 0, 0, 0);
        acc2[6  + h] = __builtin_amdgcn_mfma_f32_16x16x32_bf16(a, w3, acc2[6  + h], 0, 0, 0);
        acc2[8  + h] = __builtin_amdgcn_mfma_f32_16x16x32_bf16(a, w4, acc2[8  + h], 0, 0, 0);
        acc2[10 + h] = __builtin_amdgcn_mfma_f32_16x16x32_bf16(a, w5, acc2[10 + h], 0, 0, 0);
        acc2[12 + h] = __builtin_amdgcn_mfma_f32_16x16x32_bf16(a, w6, acc2[12 + h], 0, 0, 0);
        acc2[14 + h] = __builtin_amdgcn_mfma_f32_16x16x32_bf16(a, w7, acc2[14 + h], 0, 0, 0);
    }

    // ---- Epilogue 2 + gather: two row-half passes through sO (32x516 f32) ----
    const int prow = mw >> 1;                       // which pass this wave writes
    const int baserow2 = (mw & 1) * 16 + quad * 4;  // local row within pass

    #pragma unroll
    for (int p = 0; p < 2; ++p) {
        if (prow == p) {
            #pragma unroll
            for (int i = 0; i < 16; ++i) {
                int colp = (nw * 16 + i) * 16 + lr;           // interleaved col
                float b2v = b2[(colp >> 1) + (colp & 1) * 256];
                #pragma unroll
                for (int rr = 0; rr < 4; ++rr) {
                    float x = acc2[i][rr] + b2v;
                    sO[(baserow2 + rr) * OSD + colp] = 1.f / (1.f + __expf(-x));
                }
            }
        }
        __syncthreads();
        // gather rows p*32 .. p*32+31
        #pragma unroll
        for (int it = 0; it < 3; ++it) {
            int q4 = (it * 512 + tid) * 4;
            int rl = q4 / NJ;
            int jj = q4 - rl * NJ;
            int r  = p * 32 + rl;
            i32x4 iv = *(const i32x4*)(gidx + (b0 + (r >> 4)) * NJ + jj);
            const float* orow = sO + rl * OSD;
            f32x4 vr, vt;
            #pragma unroll
            for (int e = 0; e < 4; ++e) {
                f32x2 pr = *(const f32x2*)(orow + 2 * iv[e]);
                vr[e] = pr[0]; vt[e] = pr[1];
            }
            *(f32x4*)&out[(row0 + r) * NJ + jj]            = vr;
            *(f32x4*)&out[OUT_HALF + (row0 + r) * NJ + jj] = vt;
        }
        if (p == 0) __syncthreads();   // gather-0 reads done before pass-1 overwrites sO
    }
}

extern "C" void kernel_launch(void* const* d_in, const int* in_sizes, int n_in,
                              void* d_out, int out_size, void* d_ws, size_t ws_size,
                              hipStream_t stream) {
    const float* rgb  = (const float*)d_in[0];
    const float* tir  = (const float*)d_in[1];
    const int*   gidx = (const int*)d_in[2];
    const float* ln_g = (const float*)d_in[3];
    const float* ln_b = (const float*)d_in[4];
    const float* W1   = (const float*)d_in[5];
    const float* b1   = (const float*)d_in[6];
    const float* W2   = (const float*)d_in[7];
    const float* b2   = (const float*)d_in[8];
    float* out = (float*)d_out;
    short* wsp = (short*)d_ws;     // 512 KB: P1 at elem 0, P2 at elem 131072

    pack_weights<<<129, 256, 0, stream>>>(W1, W2, ln_g, ln_b, b1, wsp);
    fused_mlp<<<1024, 512, 0, stream>>>(rgb, tir, gidx,
                                        wsp, wsp + 131072, b2, out);
}

// Round 5
// 257.495 us; speedup vs baseline: 1.3584x; 1.0487x over previous
//
#include <hip/hip_runtime.h>
#include <stdint.h>

// Problem constants
#define NJ 192                    // N1
#define OUT_HALF 12582912         // B*HN*N1 = 4096*16*192

// LDS geometry
#define XS 520      // X: 64 x 520 bf16 (interleaved rgb/tir: col 2k=rgb_k, 2k+1=tir_k)
#define OSD 516     // O: 32 x 516 f32 per row-half pass (stride 2064B, bank shift 4)

// Arena byte layout (67584 total -> 2 blocks/CU):
//   sX    [0, 66560)        64x520 bf16, dies after A1 frag preload
//   slots [0, 32768)        four 8KB weight slots (overlay dead sX), counted-vmcnt pipe
//   sH    [32768, 65536)    64x256 bf16, 512B rows, 16B-block XOR swizzle (blk ^ (r&31))
//   sStat [67072, 67584)    64 x {rs, mu*rs} f32 (outside X; live scatter -> epi1)
//   sO    [0, 66048)        32x516 f32 overlay, after GEMM2
#define H_BYTE 32768
#define STAT_OFF 67072
#define ARENA  67584

typedef __attribute__((ext_vector_type(4)))  float    f32x4;
typedef __attribute__((ext_vector_type(16))) float    f32x16;
typedef __attribute__((ext_vector_type(2)))  float    f32x2;
typedef __attribute__((ext_vector_type(4)))  int      i32x4;
typedef __attribute__((ext_vector_type(4)))  uint32_t u32x4;
typedef __attribute__((ext_vector_type(8)))  short    bf16x8;

// u1[d] = b1[d] + sum_e W1[d][e]*ln_b[e];  v1[d] = sum_e W1[d][e]*ln_g[e]
__device__ float g_u1[256];
__device__ float g_v1[256];

__device__ __forceinline__ uint32_t cvt_pk_bf16(float lo, float hi) {
    uint32_t r;
    asm("v_cvt_pk_bf16_f32 %0, %1, %2" : "=v"(r) : "v"(lo), "v"(hi));
    return r;
}
// async global->LDS, 16B/lane; LDS dest is wave-uniform base (HW adds lane*16)
__device__ __forceinline__ void gload16(const void* g, void* l) {
    __builtin_amdgcn_global_load_lds(
        (const __attribute__((address_space(1))) uint32_t*)g,
        (__attribute__((address_space(3))) uint32_t*)l, 16, 0, 0);
}

// ---------------------------------------------------------------------------
// Pre-kernel.
//  P1: 32 units (c=K32-chunk, h=tile parity) of 8KB; unit holds 8 n-tiles
//      nt=2*t2+h, frag at unit*8192 + t2*1024 + l*16;
//      elems = W1g[nt*16+(l&15)][il K-cols c*32+(l>>4)*8 ..+7], W1g=W1*g.
//  P2 (32x32x16 B-frags): 32 units (k=K16-step, h=col-half) of 8KB;
//      unit holds 8 col-tiles t=h*8+f; frag at unit*8192 + f*1024 + l*16;
//      elems = B[k*16+(l>>5)*8+j][t*32+(l&31)], B[kk][n]=W2[orow(n)][kk],
//      n interleaved: orow = (n>>1) + (n&1)*256.
// ---------------------------------------------------------------------------
__global__ __launch_bounds__(256)
void pack_weights(const float* __restrict__ W1, const float* __restrict__ W2,
                  const float* __restrict__ ln_g, const float* __restrict__ ln_b,
                  const float* __restrict__ b1, short* __restrict__ ws) {
    if (blockIdx.x == 128) {            // u1 / v1 block
        int d = threadIdx.x;            // 0..255
        float u = b1[d], v = 0.f;
        const float* wr = W1 + d * 512;
        for (int e = 0; e < 512; e += 4) {
            f32x4 w4 = *(const f32x4*)(wr + e);
            f32x4 g4 = *(const f32x4*)(ln_g + e);
            f32x4 l4 = *(const f32x4*)(ln_b + e);
            #pragma unroll
            for (int t = 0; t < 4; ++t) { v += w4[t] * g4[t]; u += w4[t] * l4[t]; }
        }
        g_u1[d] = u; g_v1[d] = v;
        return;
    }
    int id = blockIdx.x * 256 + threadIdx.x;     // 0..32767
    if (id < 16384) {                   // P1
        int u8 = id >> 9, w = id & 511;
        int c = u8 >> 1, h = u8 & 1;
        int t2 = w >> 6, lane = w & 63;
        int nt = 2 * t2 + h;
        int row = nt * 16 + (lane & 15);
        int k0 = c * 16 + ((lane >> 4) << 2);     // orig rgb col base
        f32x4 a  = *(const f32x4*)(W1 + row * 512 + k0);
        f32x4 b  = *(const f32x4*)(W1 + row * 512 + 256 + k0);
        f32x4 ga = *(const f32x4*)(ln_g + k0);
        f32x4 gb = *(const f32x4*)(ln_g + 256 + k0);
        u32x4 o;
        #pragma unroll
        for (int t = 0; t < 4; ++t) o[t] = cvt_pk_bf16(a[t] * ga[t], b[t] * gb[t]);
        *(u32x4*)(ws + id * 8) = o;
    } else {                            // P2, 32x32x16 B layout
        int id2 = id - 16384;           // 0..16383
        int u = id2 >> 9;               // unit 0..31
        int g = id2 & 511;
        int f = g >> 6, lane = g & 63;
        int k = u >> 1, h = u & 1;
        int t = h * 8 + f;
        int n = t * 32 + (lane & 31);             // interleaved out col
        int orow = (n >> 1) + (n & 1) * 256;
        int k0 = k * 16 + ((lane >> 5) << 3);
        f32x4 a = *(const f32x4*)(W2 + orow * 256 + k0);
        f32x4 b = *(const f32x4*)(W2 + orow * 256 + k0 + 4);
        u32x4 o;
        o[0] = cvt_pk_bf16(a[0], a[1]);
        o[1] = cvt_pk_bf16(a[2], a[3]);
        o[2] = cvt_pk_bf16(b[0], b[1]);
        o[3] = cvt_pk_bf16(b[2], b[3]);
        *(u32x4*)(ws + 131072 + id2 * 8) = o;
    }
}

// ---------------------------------------------------------------------------
// Main kernel. 64 rows/block, 512 threads = 8 waves. GEMM1: 16x16x32, A-reg,
// waves 4m x 2n. GEMM2: 32x32x16, A(H) from swizzled LDS, waves 2m x 4n.
// Weights stream through four 8KB slots with counted vmcnt + raw s_barrier.
// TAIL FIX vs r4: GEMM2's last stage issues at u=28, so the queue drains;
// vmcnt(2) at u=30/31 was a NO-OP (only 2/1 loads outstanding) and the wave
// read slot data before the unit landed. Use vmcnt(min(2, 31-u)) so the
// tail actually waits for its unit. (GEMM1 never drains: seam prefetches
// P2 units at j=29..31 keep >=3 in flight.)
// ---------------------------------------------------------------------------
__global__ __launch_bounds__(512, 4)
void fused_mlp(const float* __restrict__ rgb,
               const float* __restrict__ tir,
               const int*  __restrict__ gidx,
               const short* __restrict__ P1,
               const short* __restrict__ P2,
               const float* __restrict__ b2,
               float* __restrict__ out)
{
    __shared__ __attribute__((aligned(16))) char arena[ARENA];
    short* sX    = (short*)arena;
    short* sHsh  = (short*)(arena + H_BYTE);
    float* sStat = (float*)(arena + STAT_OFF);
    float* sO    = (float*)arena;

    const int tid  = threadIdx.x;
    const int blk  = blockIdx.x;
    const int row0 = blk * 64;
    const int b0   = blk * 4;
    const int wave = tid >> 6;
    const int lane = tid & 63;
    const int lr   = lane & 15;
    const int quad = lane >> 4;
    const int mw   = wave & 3;          // GEMM1 m-tile (16 rows)
    const int nw   = wave >> 2;         // GEMM1 n-half
    const int mh   = wave >> 2;         // GEMM2 m-half (32 rows)
    const int nq   = wave & 3;          // GEMM2 n-quarter

    const char* P1b = (const char*)P1;
    const char* P2b = (const char*)P2;

    // ---- Phase 0: zero X data dwords ----
    {
        uint32_t* xd = (uint32_t*)sX;
        #pragma unroll
        for (int i = 0; i < 8; ++i) {
            int u = i * 512 + tid;
            int r = u >> 6, g = u & 63;
            *(u32x4*)(xd + r * 260 + g * 4) = (u32x4){0u, 0u, 0u, 0u};
        }
    }
    __syncthreads();

    // ---- Phase 1: fused scatter (raw bf16, rgb/tir interleaved) + LN stats ----
    {
        int r = tid >> 3, sub = tid & 7;
        int j0 = sub * 24;
        uint32_t* xdw = (uint32_t*)(sX + r * XS);
        const int*   gp = gidx + (b0 + (r >> 4)) * NJ + j0;
        const float* rp = rgb + (row0 + r) * NJ + j0;
        const float* tp = tir + (row0 + r) * NJ + j0;
        float s = 0.f, ss = 0.f;
        #pragma unroll
        for (int q = 0; q < 6; ++q) {
            i32x4 iv = *(const i32x4*)(gp + q * 4);
            f32x4 vr = *(const f32x4*)(rp + q * 4);
            f32x4 vt = *(const f32x4*)(tp + q * 4);
            #pragma unroll
            for (int e = 0; e < 4; ++e) {
                s  += vr[e] + vt[e];
                ss += vr[e] * vr[e] + vt[e] * vt[e];
                xdw[iv[e]] = cvt_pk_bf16(vr[e], vt[e]);
            }
        }
        s  += __shfl_xor(s, 1, 8);  ss += __shfl_xor(ss, 1, 8);
        s  += __shfl_xor(s, 2, 8);  ss += __shfl_xor(ss, 2, 8);
        s  += __shfl_xor(s, 4, 8);  ss += __shfl_xor(ss, 4, 8);
        float mu  = s * (1.f / 512.f);
        float var = ss * (1.f / 512.f) - mu * mu;
        float rs  = rsqrtf(var + 1e-5f);
        if (sub == 0) { sStat[2 * r] = rs; sStat[2 * r + 1] = mu * rs; }
    }
    __syncthreads();

    // ---- A1 fragments -> registers (sX dies after this) ----
    bf16x8 a1[16];
    {
        const short* xr = sX + (mw * 16 + lr) * XS + quad * 8;
        #pragma unroll
        for (int c = 0; c < 16; ++c) a1[c] = *(const bf16x8*)(xr + c * 32);
    }
    __syncthreads();                    // waits lgkmcnt(0): a1 reads done; sX dead

    // warm pipeline: P1 units 0,1,2 -> slots 0,1,2
    gload16(P1b + 0 * 8192 + tid * 16, arena + 0 * 8192 + wave * 1024);
    gload16(P1b + 1 * 8192 + tid * 16, arena + 1 * 8192 + wave * 1024);
    gload16(P1b + 2 * 8192 + tid * 16, arena + 2 * 8192 + wave * 1024);

    // ---- GEMM1: H(64x256) = X @ W1g^T, 32 units of 8KB, 16x16x32 ----
    f32x4 acc1[8];
    #pragma unroll
    for (int i = 0; i < 8; ++i) acc1[i] = (f32x4){0.f, 0.f, 0.f, 0.f};

    #pragma unroll
    for (int j = 0; j < 32; ++j) {
        const int c = j >> 1, h = j & 1;
        asm volatile("s_waitcnt vmcnt(2)" ::: "memory");   // my unit-j portion staged
        __builtin_amdgcn_s_barrier();                       // ..staged in ALL waves;
        // prev-iter slot reads complete everywhere (lgkmcnt(0) below), so the
        // stage issued now (into slot (j-1)&3) cannot pass in-flight reads.
        if (j <= 28) {
            gload16(P1b + (j + 3) * 8192 + tid * 16,
                    arena + ((j + 3) & 3) * 8192 + wave * 1024);
        } else {
            // j=29..31: prefetch P2 units 0..2 into the just-freed slots
            gload16(P2b + (j - 29) * 8192 + tid * 16,
                    arena + ((j + 3) & 3) * 8192 + wave * 1024);
        }
        const short* sb = (const short*)arena + ((j & 3) << 12);
        bf16x8 w0 = *(const bf16x8*)(sb + (nw * 4 + 0) * 512 + lane * 8);
        bf16x8 w1 = *(const bf16x8*)(sb + (nw * 4 + 1) * 512 + lane * 8);
        bf16x8 w2 = *(const bf16x8*)(sb + (nw * 4 + 2) * 512 + lane * 8);
        bf16x8 w3 = *(const bf16x8*)(sb + (nw * 4 + 3) * 512 + lane * 8);
        asm volatile("s_waitcnt lgkmcnt(0)" ::: "memory");  // reads done pre-barrier
        __builtin_amdgcn_sched_barrier(0);
        acc1[0 + h] = __builtin_amdgcn_mfma_f32_16x16x32_bf16(a1[c], w0, acc1[0 + h], 0, 0, 0);
        acc1[2 + h] = __builtin_amdgcn_mfma_f32_16x16x32_bf16(a1[c], w1, acc1[2 + h], 0, 0, 0);
        acc1[4 + h] = __builtin_amdgcn_mfma_f32_16x16x32_bf16(a1[c], w2, acc1[4 + h], 0, 0, 0);
        acc1[6 + h] = __builtin_amdgcn_mfma_f32_16x16x32_bf16(a1[c], w3, acc1[6 + h], 0, 0, 0);
    }

    // ---- Epilogue 1: h = rs*acc + (u1 - mu*rs*v1), relu -> swizzled bf16 H ----
    {
        const int baserow = mw * 16 + quad * 4;
        float rsv[4], mrs[4];
        #pragma unroll
        for (int rr = 0; rr < 4; ++rr) {
            rsv[rr] = sStat[2 * (baserow + rr)];
            mrs[rr] = sStat[2 * (baserow + rr) + 1];
        }
        #pragma unroll
        for (int i = 0; i < 8; ++i) {
            int col = (nw * 8 + i) * 16 + lr;
            int blkc = col >> 3, within = col & 7;
            float u1c = g_u1[col], v1c = g_v1[col];
            #pragma unroll
            for (int rr = 0; rr < 4; ++rr) {
                int r = baserow + rr;
                float hh = rsv[rr] * acc1[i][rr] + (u1c - mrs[rr] * v1c);
                hh = fmaxf(hh, 0.f);
                sHsh[r * 256 + ((blkc ^ (r & 31)) << 3) + within] = (short)cvt_pk_bf16(hh, hh);
            }
        }
    }
    __syncthreads();    // H visible everywhere; drains in-flight P2 units 0..2

    // ---- GEMM2: O'(64x512) = H @ W2'^T, 32 units of 8KB, 32x32x16 ----
    f32x16 acc2[4];
    #pragma unroll
    for (int i = 0; i < 4; ++i)
        #pragma unroll
        for (int e = 0; e < 16; ++e) acc2[i][e] = 0.f;

    bf16x8 a2frag;
    #pragma unroll
    for (int u = 0; u < 32; ++u) {
        const int k = u >> 1, h = u & 1;
        // TAIL FIX: last stage issues at u=28 (unit 31). For u>=30 fewer than
        // 3 loads are outstanding, so vmcnt(2) would be a no-op and the wave
        // would read unit u before it lands. Counted wait: N = min(2, 31-u).
        if (u <= 29)      asm volatile("s_waitcnt vmcnt(2)" ::: "memory");
        else if (u == 30) asm volatile("s_waitcnt vmcnt(1)" ::: "memory");
        else              asm volatile("s_waitcnt vmcnt(0)" ::: "memory");
        __builtin_amdgcn_s_barrier();
        if (u <= 28) {
            gload16(P2b + (u + 3) * 8192 + tid * 16,
                    arena + ((u + 3) & 3) * 8192 + wave * 1024);
        }
        if (h == 0) {       // A-frag reused across both col-halves of this k
            int r = mh * 32 + (lane & 31);
            int blkc = (k * 2 + (lane >> 5)) ^ (r & 31);
            a2frag = *(const bf16x8*)(sHsh + r * 256 + blkc * 8);
        }
        const short* sb = (const short*)arena + ((u & 3) << 12);
        bf16x8 bf0 = *(const bf16x8*)(sb + (nq * 2 + 0) * 512 + lane * 8);
        bf16x8 bf1 = *(const bf16x8*)(sb + (nq * 2 + 1) * 512 + lane * 8);
        asm volatile("s_waitcnt lgkmcnt(0)" ::: "memory");  // reads done pre-barrier
        __builtin_amdgcn_sched_barrier(0);
        acc2[h * 2 + 0] = __builtin_amdgcn_mfma_f32_32x32x16_bf16(a2frag, bf0, acc2[h * 2 + 0], 0, 0, 0);
        acc2[h * 2 + 1] = __builtin_amdgcn_mfma_f32_32x32x16_bf16(a2frag, bf1, acc2[h * 2 + 1], 0, 0, 0);
    }
    __syncthreads();    // all slot/H reads done before sO overlays them

    // ---- Epilogue 2 + gather: two 32-row passes through sO (32x516 f32) ----
    // 32x32 C/D layout: col = lane&31, row = (reg&3) + 8*(reg>>2) + 4*(lane>>5)
    #pragma unroll
    for (int p = 0; p < 2; ++p) {
        if (mh == p) {
            #pragma unroll
            for (int ai = 0; ai < 4; ++ai) {
                int t = (ai >> 1) * 8 + nq * 2 + (ai & 1);
                int colp = t * 32 + (lane & 31);
                float b2v = b2[(colp >> 1) + (colp & 1) * 256];
                #pragma unroll
                for (int rg = 0; rg < 16; ++rg) {
                    int lrow = (rg & 3) + 8 * (rg >> 2) + 4 * (lane >> 5);
                    float x = acc2[ai][rg] + b2v;
                    sO[lrow * OSD + colp] = 1.f / (1.f + __expf(-x));
                }
            }
        }
        __syncthreads();
        // gather rows p*32 .. p*32+31
        #pragma unroll
        for (int it = 0; it < 3; ++it) {
            int q4 = (it * 512 + tid) * 4;
            int rl = q4 / NJ;
            int jj = q4 - rl * NJ;
            int r  = p * 32 + rl;
            i32x4 iv = *(const i32x4*)(gidx + (b0 + (r >> 4)) * NJ + jj);
            const float* orow = sO + rl * OSD;
            f32x4 vr, vt;
            #pragma unroll
            for (int e = 0; e < 4; ++e) {
                f32x2 pr = *(const f32x2*)(orow + 2 * iv[e]);
                vr[e] = pr[0]; vt[e] = pr[1];
            }
            *(f32x4*)&out[(row0 + r) * NJ + jj]            = vr;
            *(f32x4*)&out[OUT_HALF + (row0 + r) * NJ + jj] = vt;
        }
        if (p == 0) __syncthreads();   // gather-0 done before pass-1 overwrites sO
    }
}

extern "C" void kernel_launch(void* const* d_in, const int* in_sizes, int n_in,
                              void* d_out, int out_size, void* d_ws, size_t ws_size,
                              hipStream_t stream) {
    const float* rgb  = (const float*)d_in[0];
    const float* tir  = (const float*)d_in[1];
    const int*   gidx = (const int*)d_in[2];
    const float* ln_g = (const float*)d_in[3];
    const float* ln_b = (const float*)d_in[4];
    const float* W1   = (const float*)d_in[5];
    const float* b1   = (const float*)d_in[6];
    const float* W2   = (const float*)d_in[7];
    const float* b2   = (const float*)d_in[8];
    float* out = (float*)d_out;
    short* wsp = (short*)d_ws;     // 512 KB: P1 at elem 0, P2 at elem 131072

    pack_weights<<<129, 256, 0, stream>>>(W1, W2, ln_g, ln_b, b1, wsp);
    fused_mlp<<<1024, 512, 0, stream>>>(rgb, tir, gidx,
                                        wsp, wsp + 131072, b2, out);
}